// Round 7
// baseline (303.719 us; speedup 1.0000x reference)
//
#include <hip/hip_runtime.h>
#include <hip/hip_bf16.h>
#include <stdint.h>

// Problem constants
#define M_B   1536      // 64*24 batch rows
#define N_L   500       // links
#define N_LP  512       // padded links (K of GEMM1, N of GEMM2)
#define N_P   20000     // paths
#define N_PP  20096     // padded paths (N of GEMM1 = 157*128, K of GEMM2)
#define N_G   4000      // OD groups
#define SPLITK 16
#define KCHUNK2 1280    // split-K chunk for GEMM2 (last = 896; both %64==0)
#define BK    64        // GEMM K-step
#define NQ    8         // row split for softmax (eighths)
#define GQ    (N_G / NQ)   // 500 groups per block
#define NCH   4         // static chunks per thread: 4*1024 = 4096 path capacity (~2500 used)

// Workspace layout (bytes). Total ~228 MB.
#define OFF_A1   ((size_t)0)                    // bf16 [1536][512]      1,572,864
#define OFF_D1   ((size_t)1572864)              // bf16 [512][20096]    20,578,304
#define OFF_DT   ((size_t)22151168)             // bf16 [20096][512]    20,578,304
#define OFF_VP   ((size_t)42729472)             // f32  [1536][20096]  123,469,824
#define OFF_F    ((size_t)166199296)            // bf16 [1536][20096]   61,734,912
#define OFF_BND  ((size_t)227934208)            // int  [4001]

typedef __bf16 bf16x8 __attribute__((ext_vector_type(8)));
typedef __bf16 bf16x4 __attribute__((ext_vector_type(4)));
typedef float  f32x4  __attribute__((ext_vector_type(4)));
typedef int    i32x4  __attribute__((ext_vector_type(4)));

__device__ __forceinline__ void gload16(const void* g, void* l) {
  __builtin_amdgcn_global_load_lds(
      (const __attribute__((address_space(1))) void*)g,
      (__attribute__((address_space(3))) void*)l, 16, 0, 0);
}

// monotonic float<->uint order-preserving mapping (for ds_max_u32-based float max)
__device__ __forceinline__ unsigned f2mono(float x) {
  unsigned u = __float_as_uint(x);
  return (u & 0x80000000u) ? ~u : (u | 0x80000000u);
}
__device__ __forceinline__ float mono2f(unsigned u) {
  u = (u & 0x80000000u) ? (u & 0x7fffffffu) : ~u;
  return __uint_as_float(u);
}

// ---- prep: v_links -> bf16 A1 [1536][512], zero-padded ----
__global__ __launch_bounds__(256) void prep_a1(const float* __restrict__ X,
                                               const float* __restrict__ theta,
                                               const float* __restrict__ theta_links,
                                               __bf16* __restrict__ A1) {
  int idx = blockIdx.x * 256 + threadIdx.x;           // over 1536*512
  if (idx >= M_B * N_LP) return;
  int b = idx >> 9, l = idx & (N_LP - 1);
  float v = 0.f;
  if (l < N_L) {
    const float* x = X + ((size_t)b * N_L + l) * 5;
#pragma unroll
    for (int f = 0; f < 5; ++f) v += x[f] * fminf(theta[f], 0.f);
    v += theta_links[l];
  }
  A1[idx] = (__bf16)v;
}

// ---- prep: D -> bf16 D1 [512][20096] (row copy) AND Dt [20096][512] (transpose) ----
__global__ __launch_bounds__(256) void prep_d(const float* __restrict__ D,
                                              __bf16* __restrict__ D1,
                                              __bf16* __restrict__ Dt) {
  __shared__ float t[32][33];
  int pb = blockIdx.x * 32;   // path block
  int lb = blockIdx.y * 32;   // link block
  for (int i = threadIdx.y; i < 32; i += 8) {
    int l = lb + i, p = pb + threadIdx.x;
    float v = (l < N_L && p < N_P) ? D[(size_t)l * N_P + p] : 0.f;
    t[i][threadIdx.x] = v;
    D1[(size_t)l * N_PP + p] = (__bf16)v;
  }
  __syncthreads();
  for (int i = threadIdx.y; i < 32; i += 8) {
    int p = pb + i, l = lb + threadIdx.x;
    Dt[(size_t)p * N_LP + l] = (__bf16)t[threadIdx.x][i];
  }
}

// ---- segment bounds: bounds[g] = first path index with seg >= g ----
__global__ __launch_bounds__(256) void seg_bounds(const int* __restrict__ seg,
                                                  int* __restrict__ bounds) {
  int g = blockIdx.x * 256 + threadIdx.x;
  if (g > N_G) return;
  int lo = 0, hi = N_P;
  while (lo < hi) { int mid = (lo + hi) >> 1; if (seg[mid] < g) lo = mid + 1; else hi = mid; }
  bounds[g] = lo;
}

// ---- GEMM (A and Bt row-major over K): C[m][n] = sum_k A[m][k]*Bt[n][k] ----
// 128x128 tile, 4 waves (2x2), BK=64 (32 MFMA per barrier pair).
// ATOMIC_OUT=0: plain f32 store (ldc). ATOMIC_OUT=1: atomicAdd into C[ldc] with col<N_L guard.
template <int ATOMIC_OUT>
__global__ __launch_bounds__(256) void gemm_bt(const __bf16* __restrict__ A,
                                               const __bf16* __restrict__ Bt,
                                               float* __restrict__ C,
                                               int lda, int ldb, int ldc,
                                               int K, int kchunk) {
  __shared__ __bf16 lsA[128 * BK];   // 16 KB
  __shared__ __bf16 lsB[128 * BK];
  const int tid = threadIdx.x;
  const int lane = tid & 63;
  const int wv = tid >> 6;
  const int wr = wv >> 1, wc = wv & 1;
  const int m0 = blockIdx.y * 128;
  const int n0 = blockIdx.x * 128;
  const int kb = blockIdx.z * kchunk;
  const int klen = min(kchunk, K - kb);

  // staging: 4 calls per matrix per K-step; call j covers rows j*32 + wv*8 + (lane>>3)
  const int srow = wv * 8 + (lane >> 3);
  const int scol = (lane & 7) * 8;
  const __bf16* gA = A + (size_t)(m0 + srow) * lda + kb + scol;
  const __bf16* gB = Bt + (size_t)(n0 + srow) * ldb + kb + scol;

  f32x4 acc[4][4] = {};
  const int fra = (wr * 64 + (lane & 15)) * BK + 8 * (lane >> 4);
  const int frb = (wc * 64 + (lane & 15)) * BK + 8 * (lane >> 4);

  for (int kk = 0; kk < klen; kk += BK) {
#pragma unroll
    for (int j = 0; j < 4; ++j) {
      gload16(gA + (size_t)(j * 32) * lda + kk, &lsA[(j * 32 + wv * 8) * BK]);
      gload16(gB + (size_t)(j * 32) * ldb + kk, &lsB[(j * 32 + wv * 8) * BK]);
    }
    __syncthreads();
#pragma unroll
    for (int t = 0; t < 2; ++t) {
      bf16x8 av[4], bv[4];
#pragma unroll
      for (int r = 0; r < 4; ++r) av[r] = *(const bf16x8*)&lsA[fra + r * 16 * BK + t * 32];
#pragma unroll
      for (int c = 0; c < 4; ++c) bv[c] = *(const bf16x8*)&lsB[frb + c * 16 * BK + t * 32];
#pragma unroll
      for (int r = 0; r < 4; ++r)
#pragma unroll
        for (int c = 0; c < 4; ++c)
          acc[r][c] = __builtin_amdgcn_mfma_f32_16x16x32_bf16(av[r], bv[c], acc[r][c], 0, 0, 0);
    }
    __syncthreads();
  }

  const int erow = m0 + wr * 64 + (lane >> 4) * 4;
  const int ecol = n0 + wc * 64 + (lane & 15);
#pragma unroll
  for (int r = 0; r < 4; ++r)
#pragma unroll
    for (int c = 0; c < 4; ++c) {
      if (ATOMIC_OUT) {
        int col = ecol + c * 16;
        if (col < N_L) {
#pragma unroll
          for (int j = 0; j < 4; ++j)
            atomicAdd(&C[(size_t)(erow + r * 16 + j) * ldc + col], acc[r][c][j]);
        }
      } else {
        float* p = C + (size_t)(erow + r * 16) * ldc + (ecol + c * 16);
#pragma unroll
        for (int j = 0; j < 4; ++j) p[(size_t)j * ldc] = acc[r][c][j];
      }
    }
}

// ---- grouped softmax: data-parallel over paths, values pinned in registers,
//      group reduce via LDS atomics. asm keep-alives stop the compiler from
//      rematerializing the vp loads across barriers (R6 bug: VGPR=24 => 3x re-read). ----
__global__ __launch_bounds__(256) void seg_softmax(const float* __restrict__ vp,
                                                   const int* __restrict__ bounds,
                                                   const int* __restrict__ seg,
                                                   const float* __restrict__ q_sqrt,
                                                   __bf16* __restrict__ f) {
  __shared__ unsigned gmaxu[GQ];
  __shared__ float    den[GQ];     // denom, then overwritten with scale q^2/denom
  const int tid = threadIdx.x;
  const int b = blockIdx.x;
  const int g0 = blockIdx.y * GQ;
  const int g1 = g0 + GQ;

  const unsigned NEGINF = f2mono(-3.4e38f);
  for (int i = tid; i < GQ; i += 256) { gmaxu[i] = NEGINF; den[i] = 0.f; }

  const int s0 = bounds[g0];
  const int e0 = (blockIdx.y == NQ - 1) ? N_P : bounds[g1];
  const int s0a = s0 & ~3;
  const int e0a = (e0 + 3) & ~3;
  const float* row = vp + (size_t)b * N_PP;

  f32x4 vv[NCH] = {};
  i32x4 sg[NCH] = {};
  __syncthreads();   // init visible

  // pass 1: coalesced load into registers + run-combine atomic max
#define AMAX(g, m) { if ((g) >= g0 && (g) < g1) atomicMax(&gmaxu[(g) - g0], f2mono(m)); }
#pragma unroll
  for (int c = 0; c < NCH; ++c) {
    int p = s0a + (c * 256 + tid) * 4;
    if (p >= e0a) continue;
    f32x4 v = *(const f32x4*)&row[p];
    vv[c] = v;
    sg[c] = *(const i32x4*)&seg[p];
    int ga = sg[c][0]; float mv = v[0];
    if (sg[c][1] == ga) mv = fmaxf(mv, v[1]); else { AMAX(ga, mv); ga = sg[c][1]; mv = v[1]; }
    if (sg[c][2] == ga) mv = fmaxf(mv, v[2]); else { AMAX(ga, mv); ga = sg[c][2]; mv = v[2]; }
    if (sg[c][3] == ga) mv = fmaxf(mv, v[3]); else { AMAX(ga, mv); ga = sg[c][3]; mv = v[3]; }
    AMAX(ga, mv);
  }
#undef AMAX
  // pin loaded values in registers across the barrier (no rematerialization)
  asm volatile("" : "+v"(vv[0]), "+v"(vv[1]), "+v"(vv[2]), "+v"(vv[3]),
                    "+v"(sg[0]), "+v"(sg[1]), "+v"(sg[2]), "+v"(sg[3]));
  __syncthreads();

  // pass 2: exp in registers (run-combined gmax lookup) + run-combine atomic add
#define AADD(g, s) { if ((g) >= g0 && (g) < g1) atomicAdd(&den[(g) - g0], s); }
#pragma unroll
  for (int c = 0; c < NCH; ++c) {
    int p = s0a + (c * 256 + tid) * 4;
    if (p >= e0a) continue;
    int grun = sg[c][0];
    bool gv = (grun >= g0 && grun < g1);
    float gm = gv ? mono2f(gmaxu[grun - g0]) : 0.f;
    float s = 0.f;
#pragma unroll
    for (int j = 0; j < 4; ++j) {
      int g = sg[c][j];
      if (g != grun) {
        AADD(grun, s);
        grun = g; s = 0.f;
        gv = (g >= g0 && g < g1);
        gm = gv ? mono2f(gmaxu[g - g0]) : 0.f;
      }
      float e = gv ? __expf(vv[c][j] - gm) : 0.f;
      vv[c][j] = e;
      s += e;
    }
    AADD(grun, s);
  }
#undef AADD
  asm volatile("" : "+v"(vv[0]), "+v"(vv[1]), "+v"(vv[2]), "+v"(vv[3]),
                    "+v"(sg[0]), "+v"(sg[1]), "+v"(sg[2]), "+v"(sg[3]));
  __syncthreads();

  // den -> scale = q^2 / den
  for (int g = tid; g < GQ; g += 256) {
    float d = den[g];
    if (d > 0.f) {
      float qs = q_sqrt[g0 + g];
      den[g] = qs * qs / d;
    }
  }
  __syncthreads();

  // pass 3: scale (run-combined lookup) + store
  __bf16* frow = f + (size_t)b * N_PP;
#pragma unroll
  for (int c = 0; c < NCH; ++c) {
    int p = s0a + (c * 256 + tid) * 4;
    if (p >= e0a) continue;
    int grun = sg[c][0];
    bool gv = (grun >= g0 && grun < g1);
    float sc = gv ? den[grun - g0] : 0.f;
    bool allv = (sg[c][0] >= g0) && (sg[c][3] < g1);
    bf16x4 o;
    bool ok[4];
#pragma unroll
    for (int j = 0; j < 4; ++j) {
      int g = sg[c][j];
      if (g != grun) {
        grun = g;
        gv = (g >= g0 && g < g1);
        sc = gv ? den[g - g0] : 0.f;
      }
      ok[j] = gv;
      o[j] = (__bf16)(vv[c][j] * sc);
    }
    if (allv) {
      *(bf16x4*)&frow[p] = o;
    } else {
#pragma unroll
      for (int j = 0; j < 4; ++j)
        if (ok[j]) frow[p + j] = o[j];
    }
  }
  // zero padded tail so GEMM2's K-padding contributes nothing
  if (blockIdx.y == NQ - 1)
    for (int p = N_P + tid; p < N_PP; p += 256) frow[p] = (__bf16)0.f;
}

extern "C" void kernel_launch(void* const* d_in, const int* in_sizes, int n_in,
                              void* d_out, int out_size, void* d_ws, size_t ws_size,
                              hipStream_t stream) {
  const float* X           = (const float*)d_in[0];
  const float* theta       = (const float*)d_in[1];
  const float* theta_links = (const float*)d_in[2];
  const float* q_sqrt      = (const float*)d_in[3];
  const float* D           = (const float*)d_in[4];
  const int*   seg         = (const int*)d_in[5];
  float* out = (float*)d_out;

  char* ws = (char*)d_ws;
  __bf16* A1   = (__bf16*)(ws + OFF_A1);
  __bf16* D1   = (__bf16*)(ws + OFF_D1);
  __bf16* Dt   = (__bf16*)(ws + OFF_DT);
  float*  vp   = (float*)(ws + OFF_VP);
  __bf16* fbuf = (__bf16*)(ws + OFF_F);
  int*    bnd  = (int*)(ws + OFF_BND);

  // out accumulated via atomics by GEMM2 -> zero it first
  hipMemsetAsync(out, 0, (size_t)M_B * N_L * sizeof(float), stream);

  prep_a1<<<(M_B * N_LP) / 256, 256, 0, stream>>>(X, theta, theta_links, A1);
  prep_d<<<dim3(N_PP / 32, N_LP / 32), dim3(32, 8), 0, stream>>>(D, D1, Dt);
  seg_bounds<<<16, 256, 0, stream>>>(seg, bnd);

  // GEMM1: vp[b][p] = sum_l A1[b][l] * Dt[p][l]
  gemm_bt<0><<<dim3(N_PP / 128, M_B / 128, 1), 256, 0, stream>>>(
      A1, Dt, vp, N_LP, N_LP, N_PP, N_LP, N_LP);

  seg_softmax<<<dim3(M_B, NQ), 256, 0, stream>>>(vp, bnd, seg, q_sqrt, fbuf);

  // GEMM2 (split-K, atomic epilogue): out[b][l] += sum_{k in chunk z} f[b][k] * D1[l][k]
  gemm_bt<1><<<dim3(N_LP / 128, M_B / 128, SPLITK), 256, 0, stream>>>(
      fbuf, D1, out, N_PP, N_PP, N_L, N_PP, KCHUNK2);
}

// Round 8
// 302.075 us; speedup vs baseline: 1.0054x; 1.0054x over previous
//
#include <hip/hip_runtime.h>
#include <hip/hip_bf16.h>
#include <stdint.h>

// Problem constants
#define M_B   1536      // 64*24 batch rows
#define N_L   500       // links
#define N_LP  512       // padded links (K of GEMM1, N of GEMM2)
#define N_P   20000     // paths
#define N_PP  20096     // padded paths (N of GEMM1 = 157*128, K of GEMM2)
#define N_G   4000      // OD groups
#define SPLITK 16
#define KCHUNK2 1280    // split-K chunk for GEMM2 (last = 896; both %32==0)
#define NQ    8         // row split for softmax (eighths)
#define GQ    (N_G / NQ)   // 500 groups per block
#define NCH   4         // static chunks per thread: 4*1024 = 4096 path capacity (~2500 used)

// Workspace layout (bytes). Total ~228 MB.
#define OFF_A1   ((size_t)0)                    // bf16 [1536][512]      1,572,864
#define OFF_D1   ((size_t)1572864)              // bf16 [512][20096]    20,578,304
#define OFF_DT   ((size_t)22151168)             // bf16 [20096][512]    20,578,304
#define OFF_VP   ((size_t)42729472)             // f32  [1536][20096]  123,469,824
#define OFF_F    ((size_t)166199296)            // bf16 [1536][20096]   61,734,912
#define OFF_BND  ((size_t)227934208)            // int  [4001]

typedef __bf16 bf16x8 __attribute__((ext_vector_type(8)));
typedef __bf16 bf16x4 __attribute__((ext_vector_type(4)));
typedef float  f32x4  __attribute__((ext_vector_type(4)));
typedef int    i32x4  __attribute__((ext_vector_type(4)));

__device__ __forceinline__ void gload16(const void* g, void* l) {
  __builtin_amdgcn_global_load_lds(
      (const __attribute__((address_space(1))) void*)g,
      (__attribute__((address_space(3))) void*)l, 16, 0, 0);
}

// monotonic float<->uint order-preserving mapping (for ds_max_u32-based float max)
__device__ __forceinline__ unsigned f2mono(float x) {
  unsigned u = __float_as_uint(x);
  return (u & 0x80000000u) ? ~u : (u | 0x80000000u);
}
__device__ __forceinline__ float mono2f(unsigned u) {
  u = (u & 0x80000000u) ? (u & 0x7fffffffu) : ~u;
  return __uint_as_float(u);
}

// ---- prep: v_links -> bf16 A1 [1536][512], zero-padded ----
__global__ __launch_bounds__(256) void prep_a1(const float* __restrict__ X,
                                               const float* __restrict__ theta,
                                               const float* __restrict__ theta_links,
                                               __bf16* __restrict__ A1) {
  int idx = blockIdx.x * 256 + threadIdx.x;           // over 1536*512
  if (idx >= M_B * N_LP) return;
  int b = idx >> 9, l = idx & (N_LP - 1);
  float v = 0.f;
  if (l < N_L) {
    const float* x = X + ((size_t)b * N_L + l) * 5;
#pragma unroll
    for (int f = 0; f < 5; ++f) v += x[f] * fminf(theta[f], 0.f);
    v += theta_links[l];
  }
  A1[idx] = (__bf16)v;
}

// ---- prep: D -> bf16 D1 [512][20096] (row copy) AND Dt [20096][512] (transpose) ----
__global__ __launch_bounds__(256) void prep_d(const float* __restrict__ D,
                                              __bf16* __restrict__ D1,
                                              __bf16* __restrict__ Dt) {
  __shared__ float t[32][33];
  int pb = blockIdx.x * 32;   // path block
  int lb = blockIdx.y * 32;   // link block
  for (int i = threadIdx.y; i < 32; i += 8) {
    int l = lb + i, p = pb + threadIdx.x;
    float v = (l < N_L && p < N_P) ? D[(size_t)l * N_P + p] : 0.f;
    t[i][threadIdx.x] = v;
    D1[(size_t)l * N_PP + p] = (__bf16)v;
  }
  __syncthreads();
  for (int i = threadIdx.y; i < 32; i += 8) {
    int p = pb + i, l = lb + threadIdx.x;
    Dt[(size_t)p * N_LP + l] = (__bf16)t[threadIdx.x][i];
  }
}

// ---- segment bounds: bounds[g] = first path index with seg >= g ----
__global__ __launch_bounds__(256) void seg_bounds(const int* __restrict__ seg,
                                                  int* __restrict__ bounds) {
  int g = blockIdx.x * 256 + threadIdx.x;
  if (g > N_G) return;
  int lo = 0, hi = N_P;
  while (lo < hi) { int mid = (lo + hi) >> 1; if (seg[mid] < g) lo = mid + 1; else hi = mid; }
  bounds[g] = lo;
}

// ---- GEMM (A and Bt row-major over K): C[m][n] = sum_k A[m][k]*Bt[n][k] ----
// 128x128 tile, 4 waves (2x2), BK=32 (m97 structure — BK=64 regressed: 16-way LDS
// conflicts + 32KB LDS occupancy loss, R7 post-mortem / m132 lesson).
// ATOMIC_OUT=0: plain f32 store. ATOMIC_OUT=1: atomicAdd into C with col<N_L guard.
template <int ATOMIC_OUT>
__global__ __launch_bounds__(256) void gemm_bt(const __bf16* __restrict__ A,
                                               const __bf16* __restrict__ Bt,
                                               float* __restrict__ C,
                                               int lda, int ldb, int ldc,
                                               int K, int kchunk) {
  __shared__ __bf16 lsA[128 * 32];
  __shared__ __bf16 lsB[128 * 32];
  const int tid = threadIdx.x;
  const int lane = tid & 63;
  const int wv = tid >> 6;
  const int wr = wv >> 1, wc = wv & 1;
  const int m0 = blockIdx.y * 128;
  const int n0 = blockIdx.x * 128;
  const int kb = blockIdx.z * kchunk;
  const int klen = min(kchunk, K - kb);

  const int srow = wv * 16 + (lane >> 2);
  const int scol = (lane & 3) * 8;
  const __bf16* gA = A + (size_t)(m0 + srow) * lda + kb + scol;
  const __bf16* gB = Bt + (size_t)(n0 + srow) * ldb + kb + scol;
  __bf16* lA0 = &lsA[(wv * 16) * 32];
  __bf16* lA1 = &lsA[(64 + wv * 16) * 32];
  __bf16* lB0 = &lsB[(wv * 16) * 32];
  __bf16* lB1 = &lsB[(64 + wv * 16) * 32];

  f32x4 acc[4][4] = {};
  const int fra = (wr * 64 + (lane & 15)) * 32 + 8 * (lane >> 4);
  const int frb = (wc * 64 + (lane & 15)) * 32 + 8 * (lane >> 4);

  for (int kk = 0; kk < klen; kk += 32) {
    gload16(gA + kk, lA0);
    gload16(gA + (size_t)64 * lda + kk, lA1);
    gload16(gB + kk, lB0);
    gload16(gB + (size_t)64 * ldb + kk, lB1);
    __syncthreads();
    bf16x8 av[4], bv[4];
#pragma unroll
    for (int r = 0; r < 4; ++r) av[r] = *(const bf16x8*)&lsA[fra + r * 16 * 32];
#pragma unroll
    for (int c = 0; c < 4; ++c) bv[c] = *(const bf16x8*)&lsB[frb + c * 16 * 32];
#pragma unroll
    for (int r = 0; r < 4; ++r)
#pragma unroll
      for (int c = 0; c < 4; ++c)
        acc[r][c] = __builtin_amdgcn_mfma_f32_16x16x32_bf16(av[r], bv[c], acc[r][c], 0, 0, 0);
    __syncthreads();
  }

  const int erow = m0 + wr * 64 + (lane >> 4) * 4;
  const int ecol = n0 + wc * 64 + (lane & 15);
#pragma unroll
  for (int r = 0; r < 4; ++r)
#pragma unroll
    for (int c = 0; c < 4; ++c) {
      if (ATOMIC_OUT) {
        int col = ecol + c * 16;
        if (col < N_L) {
#pragma unroll
          for (int j = 0; j < 4; ++j)
            atomicAdd(&C[(size_t)(erow + r * 16 + j) * ldc + col], acc[r][c][j]);
        }
      } else {
        float* p = C + (size_t)(erow + r * 16) * ldc + (ecol + c * 16);
#pragma unroll
        for (int j = 0; j < 4; ++j) p[(size_t)j * ldc] = acc[r][c][j];
      }
    }
}

// ---- grouped softmax: data-parallel over paths, values pinned in registers,
//      group reduce via LDS atomics. asm keep-alives stop the compiler from
//      rematerializing the vp loads across barriers (R6 bug: VGPR=24 => 3x re-read). ----
__global__ __launch_bounds__(256) void seg_softmax(const float* __restrict__ vp,
                                                   const int* __restrict__ bounds,
                                                   const int* __restrict__ seg,
                                                   const float* __restrict__ q_sqrt,
                                                   __bf16* __restrict__ f) {
  __shared__ unsigned gmaxu[GQ];
  __shared__ float    den[GQ];     // denom, then overwritten with scale q^2/denom
  const int tid = threadIdx.x;
  const int b = blockIdx.x;
  const int g0 = blockIdx.y * GQ;
  const int g1 = g0 + GQ;

  const unsigned NEGINF = f2mono(-3.4e38f);
  for (int i = tid; i < GQ; i += 256) { gmaxu[i] = NEGINF; den[i] = 0.f; }

  const int s0 = bounds[g0];
  const int e0 = (blockIdx.y == NQ - 1) ? N_P : bounds[g1];
  const int s0a = s0 & ~3;
  const int e0a = (e0 + 3) & ~3;
  const float* row = vp + (size_t)b * N_PP;

  f32x4 vv[NCH] = {};
  i32x4 sg[NCH] = {};
  __syncthreads();   // init visible

  // pass 1: coalesced load into registers + run-combine atomic max
#define AMAX(g, m) { if ((g) >= g0 && (g) < g1) atomicMax(&gmaxu[(g) - g0], f2mono(m)); }
#pragma unroll
  for (int c = 0; c < NCH; ++c) {
    int p = s0a + (c * 256 + tid) * 4;
    if (p >= e0a) continue;
    f32x4 v = *(const f32x4*)&row[p];
    vv[c] = v;
    sg[c] = *(const i32x4*)&seg[p];
    int ga = sg[c][0]; float mv = v[0];
    if (sg[c][1] == ga) mv = fmaxf(mv, v[1]); else { AMAX(ga, mv); ga = sg[c][1]; mv = v[1]; }
    if (sg[c][2] == ga) mv = fmaxf(mv, v[2]); else { AMAX(ga, mv); ga = sg[c][2]; mv = v[2]; }
    if (sg[c][3] == ga) mv = fmaxf(mv, v[3]); else { AMAX(ga, mv); ga = sg[c][3]; mv = v[3]; }
    AMAX(ga, mv);
  }
#undef AMAX
  // pin loaded values in registers across the barrier (no rematerialization)
  asm volatile("" : "+v"(vv[0]), "+v"(vv[1]), "+v"(vv[2]), "+v"(vv[3]),
                    "+v"(sg[0]), "+v"(sg[1]), "+v"(sg[2]), "+v"(sg[3]));
  __syncthreads();

  // pass 2: exp in registers (run-combined gmax lookup) + run-combine atomic add
#define AADD(g, s) { if ((g) >= g0 && (g) < g1) atomicAdd(&den[(g) - g0], s); }
#pragma unroll
  for (int c = 0; c < NCH; ++c) {
    int p = s0a + (c * 256 + tid) * 4;
    if (p >= e0a) continue;
    int grun = sg[c][0];
    bool gv = (grun >= g0 && grun < g1);
    float gm = gv ? mono2f(gmaxu[grun - g0]) : 0.f;
    float s = 0.f;
#pragma unroll
    for (int j = 0; j < 4; ++j) {
      int g = sg[c][j];
      if (g != grun) {
        AADD(grun, s);
        grun = g; s = 0.f;
        gv = (g >= g0 && g < g1);
        gm = gv ? mono2f(gmaxu[g - g0]) : 0.f;
      }
      float e = gv ? __expf(vv[c][j] - gm) : 0.f;
      vv[c][j] = e;
      s += e;
    }
    AADD(grun, s);
  }
#undef AADD
  asm volatile("" : "+v"(vv[0]), "+v"(vv[1]), "+v"(vv[2]), "+v"(vv[3]),
                    "+v"(sg[0]), "+v"(sg[1]), "+v"(sg[2]), "+v"(sg[3]));
  __syncthreads();

  // den -> scale = q^2 / den
  for (int g = tid; g < GQ; g += 256) {
    float d = den[g];
    if (d > 0.f) {
      float qs = q_sqrt[g0 + g];
      den[g] = qs * qs / d;
    }
  }
  __syncthreads();

  // pass 3: scale (run-combined lookup) + store
  __bf16* frow = f + (size_t)b * N_PP;
#pragma unroll
  for (int c = 0; c < NCH; ++c) {
    int p = s0a + (c * 256 + tid) * 4;
    if (p >= e0a) continue;
    int grun = sg[c][0];
    bool gv = (grun >= g0 && grun < g1);
    float sc = gv ? den[grun - g0] : 0.f;
    bool allv = (sg[c][0] >= g0) && (sg[c][3] < g1);
    bf16x4 o;
    bool ok[4];
#pragma unroll
    for (int j = 0; j < 4; ++j) {
      int g = sg[c][j];
      if (g != grun) {
        grun = g;
        gv = (g >= g0 && g < g1);
        sc = gv ? den[g - g0] : 0.f;
      }
      ok[j] = gv;
      o[j] = (__bf16)(vv[c][j] * sc);
    }
    if (allv) {
      *(bf16x4*)&frow[p] = o;
    } else {
#pragma unroll
      for (int j = 0; j < 4; ++j)
        if (ok[j]) frow[p + j] = o[j];
    }
  }
  // zero padded tail so GEMM2's K-padding contributes nothing
  if (blockIdx.y == NQ - 1)
    for (int p = N_P + tid; p < N_PP; p += 256) frow[p] = (__bf16)0.f;
}

extern "C" void kernel_launch(void* const* d_in, const int* in_sizes, int n_in,
                              void* d_out, int out_size, void* d_ws, size_t ws_size,
                              hipStream_t stream) {
  const float* X           = (const float*)d_in[0];
  const float* theta       = (const float*)d_in[1];
  const float* theta_links = (const float*)d_in[2];
  const float* q_sqrt      = (const float*)d_in[3];
  const float* D           = (const float*)d_in[4];
  const int*   seg         = (const int*)d_in[5];
  float* out = (float*)d_out;

  char* ws = (char*)d_ws;
  __bf16* A1   = (__bf16*)(ws + OFF_A1);
  __bf16* D1   = (__bf16*)(ws + OFF_D1);
  __bf16* Dt   = (__bf16*)(ws + OFF_DT);
  float*  vp   = (float*)(ws + OFF_VP);
  __bf16* fbuf = (__bf16*)(ws + OFF_F);
  int*    bnd  = (int*)(ws + OFF_BND);

  // out accumulated via atomics by GEMM2 -> zero it first
  hipMemsetAsync(out, 0, (size_t)M_B * N_L * sizeof(float), stream);

  prep_a1<<<(M_B * N_LP) / 256, 256, 0, stream>>>(X, theta, theta_links, A1);
  prep_d<<<dim3(N_PP / 32, N_LP / 32), dim3(32, 8), 0, stream>>>(D, D1, Dt);
  seg_bounds<<<16, 256, 0, stream>>>(seg, bnd);

  // GEMM1: vp[b][p] = sum_l A1[b][l] * Dt[p][l]
  gemm_bt<0><<<dim3(N_PP / 128, M_B / 128, 1), 256, 0, stream>>>(
      A1, Dt, vp, N_LP, N_LP, N_PP, N_LP, N_LP);

  seg_softmax<<<dim3(M_B, NQ), 256, 0, stream>>>(vp, bnd, seg, q_sqrt, fbuf);

  // GEMM2 (split-K, atomic epilogue): out[b][l] += sum_{k in chunk z} f[b][k] * D1[l][k]
  gemm_bt<1><<<dim3(N_LP / 128, M_B / 128, SPLITK), 256, 0, stream>>>(
      fbuf, D1, out, N_PP, N_PP, N_L, N_PP, KCHUNK2);
}

// Round 9
// 298.854 us; speedup vs baseline: 1.0163x; 1.0108x over previous
//
#include <hip/hip_runtime.h>
#include <hip/hip_bf16.h>
#include <stdint.h>

// Problem constants
#define M_B   1536      // 64*24 batch rows
#define N_L   500       // links
#define N_LP  512       // padded links (K of GEMM1, N of GEMM2)
#define N_P   20000     // paths
#define N_PP  20096     // padded paths (N of GEMM1 = 157*128, K of GEMM2)
#define N_G   4000      // OD groups
#define SPLITK 16
#define KCHUNK2 1280    // split-K chunk for GEMM2 (last = 896; both %32==0)
#define SM_ROWS 16      // rows per softmax block (grid.y = 96)

// Workspace layout (bytes). Total ~228 MB. part aliases vp (vp dead after softmax).
#define OFF_A1   ((size_t)0)                    // bf16 [1536][512]      1,572,864
#define OFF_D1   ((size_t)1572864)              // bf16 [512][20096]    20,578,304
#define OFF_DT   ((size_t)22151168)             // bf16 [20096][512]    20,578,304
#define OFF_VP   ((size_t)42729472)             // f32  [1536][20096]  123,469,824
#define OFF_PART OFF_VP                         // f32  [16][1536][512] 50,331,648 (aliases vp)
#define OFF_F    ((size_t)166199296)            // bf16 [1536][20096]   61,734,912
#define OFF_BND  ((size_t)227934208)            // int  [4001]

typedef __bf16 bf16x8 __attribute__((ext_vector_type(8)));
typedef float  f32x4  __attribute__((ext_vector_type(4)));

__device__ __forceinline__ void gload16(const void* g, void* l) {
  __builtin_amdgcn_global_load_lds(
      (const __attribute__((address_space(1))) void*)g,
      (__attribute__((address_space(3))) void*)l, 16, 0, 0);
}

// ---- prep: v_links -> bf16 A1 [1536][512], zero-padded ----
__global__ __launch_bounds__(256) void prep_a1(const float* __restrict__ X,
                                               const float* __restrict__ theta,
                                               const float* __restrict__ theta_links,
                                               __bf16* __restrict__ A1) {
  int idx = blockIdx.x * 256 + threadIdx.x;           // over 1536*512
  if (idx >= M_B * N_LP) return;
  int b = idx >> 9, l = idx & (N_LP - 1);
  float v = 0.f;
  if (l < N_L) {
    const float* x = X + ((size_t)b * N_L + l) * 5;
#pragma unroll
    for (int f = 0; f < 5; ++f) v += x[f] * fminf(theta[f], 0.f);
    v += theta_links[l];
  }
  A1[idx] = (__bf16)v;
}

// ---- prep: D -> bf16 D1 [512][20096] (row copy) AND Dt [20096][512] (transpose) ----
__global__ __launch_bounds__(256) void prep_d(const float* __restrict__ D,
                                              __bf16* __restrict__ D1,
                                              __bf16* __restrict__ Dt) {
  __shared__ float t[32][33];
  int pb = blockIdx.x * 32;   // path block
  int lb = blockIdx.y * 32;   // link block
  for (int i = threadIdx.y; i < 32; i += 8) {
    int l = lb + i, p = pb + threadIdx.x;
    float v = (l < N_L && p < N_P) ? D[(size_t)l * N_P + p] : 0.f;
    t[i][threadIdx.x] = v;
    D1[(size_t)l * N_PP + p] = (__bf16)v;
  }
  __syncthreads();
  for (int i = threadIdx.y; i < 32; i += 8) {
    int p = pb + i, l = lb + threadIdx.x;
    Dt[(size_t)p * N_LP + l] = (__bf16)t[threadIdx.x][i];
  }
}

// ---- segment bounds: bounds[g] = first path index with seg >= g ----
__global__ __launch_bounds__(256) void seg_bounds(const int* __restrict__ seg,
                                                  int* __restrict__ bounds) {
  int g = blockIdx.x * 256 + threadIdx.x;
  if (g > N_G) return;
  int lo = 0, hi = N_P;
  while (lo < hi) { int mid = (lo + hi) >> 1; if (seg[mid] < g) lo = mid + 1; else hi = mid; }
  bounds[g] = lo;
}

// ---- GEMM (A and Bt row-major over K): C[m][n] = sum_k A[m][k]*Bt[n][k] ----
// 128x128 tile, 4 waves (2x2), BK=32 (m97 structure; BK=64 regressed — R7/m132).
// ZSWZ=1: 1-D grid, z = bid&15 so XCD (= bid%8) pins z%8 -> each XCD's 2 K-chunks
// keep their D1 slices (~2.6 MB) L2-resident instead of 8x re-fetch.
template <int ZSWZ>
__global__ __launch_bounds__(256) void gemm_bt(const __bf16* __restrict__ A,
                                               const __bf16* __restrict__ Bt,
                                               float* __restrict__ C,
                                               int lda, int ldb, int ldc,
                                               int K, int kchunk, size_t zstride) {
  int bx, by, bz;
  if (ZSWZ) { int bid = blockIdx.x; bz = bid & 15; bx = (bid >> 4) & 3; by = bid >> 6; }
  else      { bx = blockIdx.x; by = blockIdx.y; bz = blockIdx.z; }
  __shared__ __bf16 lsA[128 * 32];
  __shared__ __bf16 lsB[128 * 32];
  const int tid = threadIdx.x;
  const int lane = tid & 63;
  const int wv = tid >> 6;
  const int wr = wv >> 1, wc = wv & 1;
  const int m0 = by * 128;
  const int n0 = bx * 128;
  const int kb = bz * kchunk;
  const int klen = min(kchunk, K - kb);

  const int srow = wv * 16 + (lane >> 2);
  const int scol = (lane & 3) * 8;
  const __bf16* gA = A + (size_t)(m0 + srow) * lda + kb + scol;
  const __bf16* gB = Bt + (size_t)(n0 + srow) * ldb + kb + scol;
  __bf16* lA0 = &lsA[(wv * 16) * 32];
  __bf16* lA1 = &lsA[(64 + wv * 16) * 32];
  __bf16* lB0 = &lsB[(wv * 16) * 32];
  __bf16* lB1 = &lsB[(64 + wv * 16) * 32];

  f32x4 acc[4][4] = {};
  const int fra = (wr * 64 + (lane & 15)) * 32 + 8 * (lane >> 4);
  const int frb = (wc * 64 + (lane & 15)) * 32 + 8 * (lane >> 4);

  for (int kk = 0; kk < klen; kk += 32) {
    gload16(gA + kk, lA0);
    gload16(gA + (size_t)64 * lda + kk, lA1);
    gload16(gB + kk, lB0);
    gload16(gB + (size_t)64 * ldb + kk, lB1);
    __syncthreads();
    bf16x8 av[4], bv[4];
#pragma unroll
    for (int r = 0; r < 4; ++r) av[r] = *(const bf16x8*)&lsA[fra + r * 16 * 32];
#pragma unroll
    for (int c = 0; c < 4; ++c) bv[c] = *(const bf16x8*)&lsB[frb + c * 16 * 32];
#pragma unroll
    for (int r = 0; r < 4; ++r)
#pragma unroll
      for (int c = 0; c < 4; ++c)
        acc[r][c] = __builtin_amdgcn_mfma_f32_16x16x32_bf16(av[r], bv[c], acc[r][c], 0, 0, 0);
    __syncthreads();
  }

  float* Cz = C + (size_t)bz * zstride;
  const int erow = m0 + wr * 64 + (lane >> 4) * 4;
  const int ecol = n0 + wc * 64 + (lane & 15);
#pragma unroll
  for (int r = 0; r < 4; ++r)
#pragma unroll
    for (int c = 0; c < 4; ++c) {
      float* p = Cz + (size_t)(erow + r * 16) * ldc + (ecol + c * 16);
#pragma unroll
      for (int j = 0; j < 4; ++j) p[(size_t)j * ldc] = acc[r][c][j];
    }
}

// ---- grouped softmax: one GROUP per thread, SM_ROWS rows per block. ----
// Groups are contiguous (~5 paths); thread keeps s,e,q^2 in registers across rows.
// Three short walks per (row,group): max (HBM read), exp+sum (L1-hot), store
// (L1-hot, recompute exp). No LDS, no atomics, no barriers, no seg loads.
__global__ __launch_bounds__(256) void seg_softmax_g(const float* __restrict__ vp,
                                                     const int* __restrict__ bounds,
                                                     const float* __restrict__ q_sqrt,
                                                     __bf16* __restrict__ f) {
  const int g = blockIdx.x * 256 + threadIdx.x;   // grid.x = 16 -> g in [0,4096)
  const int r0 = blockIdx.y * SM_ROWS;
  int s = 0, e = 0;
  float q2 = 0.f;
  if (g < N_G) {
    s = bounds[g];
    e = bounds[g + 1];
    float qs = q_sqrt[g];
    q2 = qs * qs;
  }
  // threads with g in [4000,4096) zero the 96 padded columns instead
  const int pz = (g >= N_G) ? N_P + (g - N_G) : -1;

  for (int r = r0; r < r0 + SM_ROWS; ++r) {
    const float* row = vp + (size_t)r * N_PP;
    __bf16* frow = f + (size_t)r * N_PP;
    float m = -3.4e38f;
    for (int p = s; p < e; ++p) m = fmaxf(m, row[p]);
    float den = 0.f;
    for (int p = s; p < e; ++p) den += __expf(row[p] - m);
    float sc = (den > 0.f) ? q2 / den : 0.f;
    for (int p = s; p < e; ++p) frow[p] = (__bf16)(__expf(row[p] - m) * sc);
    if (pz >= 0) frow[pz] = (__bf16)0.f;
  }
}

// ---- reduce split-K partials -> out (only l < 500) ----
__global__ __launch_bounds__(256) void reduce_out(const float* __restrict__ part,
                                                  float* __restrict__ out) {
  int idx = blockIdx.x * 256 + threadIdx.x;   // over 1536*500
  if (idx >= M_B * N_L) return;
  int b = idx / N_L, l = idx - b * N_L;
  float s = 0.f;
#pragma unroll
  for (int z = 0; z < SPLITK; ++z)
    s += part[(size_t)z * M_B * N_LP + (size_t)b * N_LP + l];
  out[idx] = s;
}

extern "C" void kernel_launch(void* const* d_in, const int* in_sizes, int n_in,
                              void* d_out, int out_size, void* d_ws, size_t ws_size,
                              hipStream_t stream) {
  const float* X           = (const float*)d_in[0];
  const float* theta       = (const float*)d_in[1];
  const float* theta_links = (const float*)d_in[2];
  const float* q_sqrt      = (const float*)d_in[3];
  const float* D           = (const float*)d_in[4];
  const int*   seg         = (const int*)d_in[5];
  float* out = (float*)d_out;

  char* ws = (char*)d_ws;
  __bf16* A1   = (__bf16*)(ws + OFF_A1);
  __bf16* D1   = (__bf16*)(ws + OFF_D1);
  __bf16* Dt   = (__bf16*)(ws + OFF_DT);
  float*  vp   = (float*)(ws + OFF_VP);
  float*  part = (float*)(ws + OFF_PART);
  __bf16* fbuf = (__bf16*)(ws + OFF_F);
  int*    bnd  = (int*)(ws + OFF_BND);

  prep_a1<<<(M_B * N_LP) / 256, 256, 0, stream>>>(X, theta, theta_links, A1);
  prep_d<<<dim3(N_PP / 32, N_LP / 32), dim3(32, 8), 0, stream>>>(D, D1, Dt);
  seg_bounds<<<16, 256, 0, stream>>>(seg, bnd);

  // GEMM1: vp[b][p] = sum_l A1[b][l] * Dt[p][l]
  gemm_bt<0><<<dim3(N_PP / 128, M_B / 128, 1), 256, 0, stream>>>(
      A1, Dt, vp, N_LP, N_LP, N_PP, N_LP, N_LP, (size_t)0);

  // softmax: grid (16 group-blocks, 96 row-chunks)
  seg_softmax_g<<<dim3(16, M_B / SM_ROWS), 256, 0, stream>>>(vp, bnd, q_sqrt, fbuf);

  // GEMM2 (split-K, z-swizzled 1-D grid): part[z][b][l] = sum_{k in z} f[b][k]*D1[l][k]
  gemm_bt<1><<<dim3((N_LP / 128) * (M_B / 128) * SPLITK, 1, 1), 256, 0, stream>>>(
      fbuf, D1, part, N_PP, N_PP, N_LP, N_PP, KCHUNK2, (size_t)(M_B * N_LP));

  reduce_out<<<(M_B * N_L + 255) / 256, 256, 0, stream>>>(part, out);
}

// Round 10
// 247.147 us; speedup vs baseline: 1.2289x; 1.2092x over previous
//
#include <hip/hip_runtime.h>
#include <hip/hip_bf16.h>
#include <stdint.h>

// Problem constants
#define M_B   1536      // 64*24 batch rows
#define N_L   500       // links
#define N_LP  512       // padded links (K of GEMM1, N of GEMM2)
#define N_P   20000     // paths
#define N_PP  20096     // padded paths (N of GEMM1 = 157*128, K of GEMM2)
#define N_G   4000      // OD groups
#define SPLITK 16
#define KCHUNK2 1280    // split-K chunk for GEMM2 (last = 896; both %32==0)
#define NQ    8         // row split for softmax (eighths)
#define GQ    (N_G / NQ)   // 500 groups per block
#define NCH   4         // static chunks per thread: 4*1024 = 4096 path capacity (~2500 used)

// Workspace layout (bytes). Total ~228 MB. part aliases vp (vp dead after softmax).
#define OFF_A1   ((size_t)0)                    // bf16 [1536][512]      1,572,864
#define OFF_D1   ((size_t)1572864)              // bf16 [512][20096]    20,578,304
#define OFF_DT   ((size_t)22151168)             // bf16 [20096][512]    20,578,304
#define OFF_VP   ((size_t)42729472)             // f32  [1536][20096]  123,469,824
#define OFF_PART OFF_VP                         // f32  [16][1536][512] 50,331,648 (aliases vp)
#define OFF_F    ((size_t)166199296)            // bf16 [1536][20096]   61,734,912
#define OFF_BND  ((size_t)227934208)            // int  [4001]

typedef __bf16 bf16x8 __attribute__((ext_vector_type(8)));
typedef __bf16 bf16x4 __attribute__((ext_vector_type(4)));
typedef float  f32x4  __attribute__((ext_vector_type(4)));
typedef int    i32x4  __attribute__((ext_vector_type(4)));

__device__ __forceinline__ void gload16(const void* g, void* l) {
  __builtin_amdgcn_global_load_lds(
      (const __attribute__((address_space(1))) void*)g,
      (__attribute__((address_space(3))) void*)l, 16, 0, 0);
}

// monotonic float<->uint order-preserving mapping (for ds_max_u32-based float max)
__device__ __forceinline__ unsigned f2mono(float x) {
  unsigned u = __float_as_uint(x);
  return (u & 0x80000000u) ? ~u : (u | 0x80000000u);
}
__device__ __forceinline__ float mono2f(unsigned u) {
  u = (u & 0x80000000u) ? (u & 0x7fffffffu) : ~u;
  return __uint_as_float(u);
}

// ---- prep: v_links -> bf16 A1 [1536][512], zero-padded ----
__global__ __launch_bounds__(256) void prep_a1(const float* __restrict__ X,
                                               const float* __restrict__ theta,
                                               const float* __restrict__ theta_links,
                                               __bf16* __restrict__ A1) {
  int idx = blockIdx.x * 256 + threadIdx.x;           // over 1536*512
  if (idx >= M_B * N_LP) return;
  int b = idx >> 9, l = idx & (N_LP - 1);
  float v = 0.f;
  if (l < N_L) {
    const float* x = X + ((size_t)b * N_L + l) * 5;
#pragma unroll
    for (int f = 0; f < 5; ++f) v += x[f] * fminf(theta[f], 0.f);
    v += theta_links[l];
  }
  A1[idx] = (__bf16)v;
}

// ---- prep: D -> bf16 D1 [512][20096] (row copy) AND Dt [20096][512] (transpose) ----
__global__ __launch_bounds__(256) void prep_d(const float* __restrict__ D,
                                              __bf16* __restrict__ D1,
                                              __bf16* __restrict__ Dt) {
  __shared__ float t[32][33];
  int pb = blockIdx.x * 32;   // path block
  int lb = blockIdx.y * 32;   // link block
  for (int i = threadIdx.y; i < 32; i += 8) {
    int l = lb + i, p = pb + threadIdx.x;
    float v = (l < N_L && p < N_P) ? D[(size_t)l * N_P + p] : 0.f;
    t[i][threadIdx.x] = v;
    D1[(size_t)l * N_PP + p] = (__bf16)v;
  }
  __syncthreads();
  for (int i = threadIdx.y; i < 32; i += 8) {
    int p = pb + i, l = lb + threadIdx.x;
    Dt[(size_t)p * N_LP + l] = (__bf16)t[threadIdx.x][i];
  }
}

// ---- segment bounds: bounds[g] = first path index with seg >= g ----
__global__ __launch_bounds__(256) void seg_bounds(const int* __restrict__ seg,
                                                  int* __restrict__ bounds) {
  int g = blockIdx.x * 256 + threadIdx.x;
  if (g > N_G) return;
  int lo = 0, hi = N_P;
  while (lo < hi) { int mid = (lo + hi) >> 1; if (seg[mid] < g) lo = mid + 1; else hi = mid; }
  bounds[g] = lo;
}

// ---- GEMM (A and Bt row-major over K): C[m][n] = sum_k A[m][k]*Bt[n][k] ----
// 128x128 tile, 4 waves (2x2), BK=32 (m97 structure; BK=64 refuted R7/m132).
// ZSWZ=1: 1-D grid, z = bid&15 so XCD (= bid%8) pins z%8 -> each XCD's 2 K-chunks
// keep their D1 slices (~2.6 MB) L2-resident.
template <int ZSWZ>
__global__ __launch_bounds__(256) void gemm_bt(const __bf16* __restrict__ A,
                                               const __bf16* __restrict__ Bt,
                                               float* __restrict__ C,
                                               int lda, int ldb, int ldc,
                                               int K, int kchunk, size_t zstride) {
  int bx, by, bz;
  if (ZSWZ) { int bid = blockIdx.x; bz = bid & 15; bx = (bid >> 4) & 3; by = bid >> 6; }
  else      { bx = blockIdx.x; by = blockIdx.y; bz = blockIdx.z; }
  __shared__ __bf16 lsA[128 * 32];
  __shared__ __bf16 lsB[128 * 32];
  const int tid = threadIdx.x;
  const int lane = tid & 63;
  const int wv = tid >> 6;
  const int wr = wv >> 1, wc = wv & 1;
  const int m0 = by * 128;
  const int n0 = bx * 128;
  const int kb = bz * kchunk;
  const int klen = min(kchunk, K - kb);

  const int srow = wv * 16 + (lane >> 2);
  const int scol = (lane & 3) * 8;
  const __bf16* gA = A + (size_t)(m0 + srow) * lda + kb + scol;
  const __bf16* gB = Bt + (size_t)(n0 + srow) * ldb + kb + scol;
  __bf16* lA0 = &lsA[(wv * 16) * 32];
  __bf16* lA1 = &lsA[(64 + wv * 16) * 32];
  __bf16* lB0 = &lsB[(wv * 16) * 32];
  __bf16* lB1 = &lsB[(64 + wv * 16) * 32];

  f32x4 acc[4][4] = {};
  const int fra = (wr * 64 + (lane & 15)) * 32 + 8 * (lane >> 4);
  const int frb = (wc * 64 + (lane & 15)) * 32 + 8 * (lane >> 4);

  for (int kk = 0; kk < klen; kk += 32) {
    gload16(gA + kk, lA0);
    gload16(gA + (size_t)64 * lda + kk, lA1);
    gload16(gB + kk, lB0);
    gload16(gB + (size_t)64 * ldb + kk, lB1);
    __syncthreads();
    bf16x8 av[4], bv[4];
#pragma unroll
    for (int r = 0; r < 4; ++r) av[r] = *(const bf16x8*)&lsA[fra + r * 16 * 32];
#pragma unroll
    for (int c = 0; c < 4; ++c) bv[c] = *(const bf16x8*)&lsB[frb + c * 16 * 32];
#pragma unroll
    for (int r = 0; r < 4; ++r)
#pragma unroll
      for (int c = 0; c < 4; ++c)
        acc[r][c] = __builtin_amdgcn_mfma_f32_16x16x32_bf16(av[r], bv[c], acc[r][c], 0, 0, 0);
    __syncthreads();
  }

  float* Cz = C + (size_t)bz * zstride;
  const int erow = m0 + wr * 64 + (lane >> 4) * 4;
  const int ecol = n0 + wc * 64 + (lane & 15);
#pragma unroll
  for (int r = 0; r < 4; ++r)
#pragma unroll
    for (int c = 0; c < 4; ++c) {
      float* p = Cz + (size_t)(erow + r * 16) * ldc + (ecol + c * 16);
#pragma unroll
      for (int j = 0; j < 4; ++j) p[(size_t)j * ldc] = acc[r][c][j];
    }
}

// ---- grouped softmax: data-parallel over paths, values pinned in registers,
//      group reduce via LDS atomics. asm keep-alives stop rematerialization
//      (R6 bug: VGPR=24 => 3x vp re-read). Best measured softmax (R7/R8). ----
__global__ __launch_bounds__(256) void seg_softmax(const float* __restrict__ vp,
                                                   const int* __restrict__ bounds,
                                                   const int* __restrict__ seg,
                                                   const float* __restrict__ q_sqrt,
                                                   __bf16* __restrict__ f) {
  __shared__ unsigned gmaxu[GQ];
  __shared__ float    den[GQ];     // denom, then overwritten with scale q^2/denom
  const int tid = threadIdx.x;
  const int b = blockIdx.x;
  const int g0 = blockIdx.y * GQ;
  const int g1 = g0 + GQ;

  const unsigned NEGINF = f2mono(-3.4e38f);
  for (int i = tid; i < GQ; i += 256) { gmaxu[i] = NEGINF; den[i] = 0.f; }

  const int s0 = bounds[g0];
  const int e0 = (blockIdx.y == NQ - 1) ? N_P : bounds[g1];
  const int s0a = s0 & ~3;
  const int e0a = (e0 + 3) & ~3;
  const float* row = vp + (size_t)b * N_PP;

  f32x4 vv[NCH] = {};
  i32x4 sg[NCH] = {};
  __syncthreads();   // init visible

  // pass 1: coalesced load into registers + run-combine atomic max
#define AMAX(g, m) { if ((g) >= g0 && (g) < g1) atomicMax(&gmaxu[(g) - g0], f2mono(m)); }
#pragma unroll
  for (int c = 0; c < NCH; ++c) {
    int p = s0a + (c * 256 + tid) * 4;
    if (p >= e0a) continue;
    f32x4 v = *(const f32x4*)&row[p];
    vv[c] = v;
    sg[c] = *(const i32x4*)&seg[p];
    int ga = sg[c][0]; float mv = v[0];
    if (sg[c][1] == ga) mv = fmaxf(mv, v[1]); else { AMAX(ga, mv); ga = sg[c][1]; mv = v[1]; }
    if (sg[c][2] == ga) mv = fmaxf(mv, v[2]); else { AMAX(ga, mv); ga = sg[c][2]; mv = v[2]; }
    if (sg[c][3] == ga) mv = fmaxf(mv, v[3]); else { AMAX(ga, mv); ga = sg[c][3]; mv = v[3]; }
    AMAX(ga, mv);
  }
#undef AMAX
  // pin loaded values in registers across the barrier (no rematerialization)
  asm volatile("" : "+v"(vv[0]), "+v"(vv[1]), "+v"(vv[2]), "+v"(vv[3]),
                    "+v"(sg[0]), "+v"(sg[1]), "+v"(sg[2]), "+v"(sg[3]));
  __syncthreads();

  // pass 2: exp in registers (run-combined gmax lookup) + run-combine atomic add
#define AADD(g, s) { if ((g) >= g0 && (g) < g1) atomicAdd(&den[(g) - g0], s); }
#pragma unroll
  for (int c = 0; c < NCH; ++c) {
    int p = s0a + (c * 256 + tid) * 4;
    if (p >= e0a) continue;
    int grun = sg[c][0];
    bool gv = (grun >= g0 && grun < g1);
    float gm = gv ? mono2f(gmaxu[grun - g0]) : 0.f;
    float s = 0.f;
#pragma unroll
    for (int j = 0; j < 4; ++j) {
      int g = sg[c][j];
      if (g != grun) {
        AADD(grun, s);
        grun = g; s = 0.f;
        gv = (g >= g0 && g < g1);
        gm = gv ? mono2f(gmaxu[g - g0]) : 0.f;
      }
      float e = gv ? __expf(vv[c][j] - gm) : 0.f;
      vv[c][j] = e;
      s += e;
    }
    AADD(grun, s);
  }
#undef AADD
  asm volatile("" : "+v"(vv[0]), "+v"(vv[1]), "+v"(vv[2]), "+v"(vv[3]),
                    "+v"(sg[0]), "+v"(sg[1]), "+v"(sg[2]), "+v"(sg[3]));
  __syncthreads();

  // den -> scale = q^2 / den
  for (int g = tid; g < GQ; g += 256) {
    float d = den[g];
    if (d > 0.f) {
      float qs = q_sqrt[g0 + g];
      den[g] = qs * qs / d;
    }
  }
  __syncthreads();

  // pass 3: scale (run-combined lookup) + store
  __bf16* frow = f + (size_t)b * N_PP;
#pragma unroll
  for (int c = 0; c < NCH; ++c) {
    int p = s0a + (c * 256 + tid) * 4;
    if (p >= e0a) continue;
    int grun = sg[c][0];
    bool gv = (grun >= g0 && grun < g1);
    float sc = gv ? den[grun - g0] : 0.f;
    bool allv = (sg[c][0] >= g0) && (sg[c][3] < g1);
    bf16x4 o;
    bool ok[4];
#pragma unroll
    for (int j = 0; j < 4; ++j) {
      int g = sg[c][j];
      if (g != grun) {
        grun = g;
        gv = (g >= g0 && g < g1);
        sc = gv ? den[g - g0] : 0.f;
      }
      ok[j] = gv;
      o[j] = (__bf16)(vv[c][j] * sc);
    }
    if (allv) {
      *(bf16x4*)&frow[p] = o;
    } else {
#pragma unroll
      for (int j = 0; j < 4; ++j)
        if (ok[j]) frow[p + j] = o[j];
    }
  }
  // zero padded tail so GEMM2's K-padding contributes nothing
  if (blockIdx.y == NQ - 1)
    for (int p = N_P + tid; p < N_PP; p += 256) frow[p] = (__bf16)0.f;
}

// ---- reduce split-K partials -> out (only l < 500) ----
__global__ __launch_bounds__(256) void reduce_out(const float* __restrict__ part,
                                                  float* __restrict__ out) {
  int idx = blockIdx.x * 256 + threadIdx.x;   // over 1536*500
  if (idx >= M_B * N_L) return;
  int b = idx / N_L, l = idx - b * N_L;
  float s = 0.f;
#pragma unroll
  for (int z = 0; z < SPLITK; ++z)
    s += part[(size_t)z * M_B * N_LP + (size_t)b * N_LP + l];
  out[idx] = s;
}

extern "C" void kernel_launch(void* const* d_in, const int* in_sizes, int n_in,
                              void* d_out, int out_size, void* d_ws, size_t ws_size,
                              hipStream_t stream) {
  const float* X           = (const float*)d_in[0];
  const float* theta       = (const float*)d_in[1];
  const float* theta_links = (const float*)d_in[2];
  const float* q_sqrt      = (const float*)d_in[3];
  const float* D           = (const float*)d_in[4];
  const int*   seg         = (const int*)d_in[5];
  float* out = (float*)d_out;

  char* ws = (char*)d_ws;
  __bf16* A1   = (__bf16*)(ws + OFF_A1);
  __bf16* D1   = (__bf16*)(ws + OFF_D1);
  __bf16* Dt   = (__bf16*)(ws + OFF_DT);
  float*  vp   = (float*)(ws + OFF_VP);
  float*  part = (float*)(ws + OFF_PART);
  __bf16* fbuf = (__bf16*)(ws + OFF_F);
  int*    bnd  = (int*)(ws + OFF_BND);

  prep_a1<<<(M_B * N_LP) / 256, 256, 0, stream>>>(X, theta, theta_links, A1);
  prep_d<<<dim3(N_PP / 32, N_LP / 32), dim3(32, 8), 0, stream>>>(D, D1, Dt);
  seg_bounds<<<16, 256, 0, stream>>>(seg, bnd);

  // GEMM1: vp[b][p] = sum_l A1[b][l] * Dt[p][l]
  gemm_bt<0><<<dim3(N_PP / 128, M_B / 128, 1), 256, 0, stream>>>(
      A1, Dt, vp, N_LP, N_LP, N_PP, N_LP, N_LP, (size_t)0);

  seg_softmax<<<dim3(M_B, NQ), 256, 0, stream>>>(vp, bnd, seg, q_sqrt, fbuf);

  // GEMM2 (split-K, z-swizzled 1-D grid): part[z][b][l] = sum_{k in z} f[b][k]*D1[l][k]
  gemm_bt<1><<<dim3((N_LP / 128) * (M_B / 128) * SPLITK, 1, 1), 256, 0, stream>>>(
      fbuf, D1, part, N_PP, N_PP, N_LP, N_PP, KCHUNK2, (size_t)(M_B * N_LP));

  reduce_out<<<(M_B * N_L + 255) / 256, 256, 0, stream>>>(part, out);
}

// Round 11
// 245.915 us; speedup vs baseline: 1.2351x; 1.0050x over previous
//
#include <hip/hip_runtime.h>
#include <hip/hip_bf16.h>
#include <stdint.h>

// Problem constants
#define M_B   1536      // 64*24 batch rows
#define N_L   500       // links
#define N_LP  512       // padded links (K of GEMM1, N of GEMM2)
#define N_P   20000     // paths
#define N_PP  20096     // padded paths (N of GEMM1 = 157*128, K of GEMM2)
#define N_G   4000      // OD groups
#define SPLITK 16
#define KCHUNK2 1280    // split-K chunk for GEMM2 (last = 896; both %32==0)
#define NQW   32        // row split for softmax (1-wave blocks)
#define GQW   (N_G / NQW)  // 125 groups per block
#define NCH   4         // static chunks per thread: 4*256 = 1024 path capacity (~625 used, +16 sigma)

// Workspace layout (bytes). Total ~228 MB. part aliases vp (vp dead after softmax).
#define OFF_A1   ((size_t)0)                    // bf16 [1536][512]      1,572,864
#define OFF_D1   ((size_t)1572864)              // bf16 [512][20096]    20,578,304
#define OFF_DT   ((size_t)22151168)             // bf16 [20096][512]    20,578,304
#define OFF_VP   ((size_t)42729472)             // f32  [1536][20096]  123,469,824
#define OFF_PART OFF_VP                         // f32  [16][1536][512] 50,331,648 (aliases vp)
#define OFF_F    ((size_t)166199296)            // bf16 [1536][20096]   61,734,912
#define OFF_BND  ((size_t)227934208)            // int  [4001]

typedef __bf16 bf16x8 __attribute__((ext_vector_type(8)));
typedef __bf16 bf16x4 __attribute__((ext_vector_type(4)));
typedef float  f32x4  __attribute__((ext_vector_type(4)));
typedef int    i32x4  __attribute__((ext_vector_type(4)));

__device__ __forceinline__ void gload16(const void* g, void* l) {
  __builtin_amdgcn_global_load_lds(
      (const __attribute__((address_space(1))) void*)g,
      (__attribute__((address_space(3))) void*)l, 16, 0, 0);
}

// monotonic float<->uint order-preserving mapping (for ds_max_u32-based float max)
__device__ __forceinline__ unsigned f2mono(float x) {
  unsigned u = __float_as_uint(x);
  return (u & 0x80000000u) ? ~u : (u | 0x80000000u);
}
__device__ __forceinline__ float mono2f(unsigned u) {
  u = (u & 0x80000000u) ? (u & 0x7fffffffu) : ~u;
  return __uint_as_float(u);
}

// ---- prep: v_links -> bf16 A1 [1536][512], zero-padded ----
__global__ __launch_bounds__(256) void prep_a1(const float* __restrict__ X,
                                               const float* __restrict__ theta,
                                               const float* __restrict__ theta_links,
                                               __bf16* __restrict__ A1) {
  int idx = blockIdx.x * 256 + threadIdx.x;           // over 1536*512
  if (idx >= M_B * N_LP) return;
  int b = idx >> 9, l = idx & (N_LP - 1);
  float v = 0.f;
  if (l < N_L) {
    const float* x = X + ((size_t)b * N_L + l) * 5;
#pragma unroll
    for (int f = 0; f < 5; ++f) v += x[f] * fminf(theta[f], 0.f);
    v += theta_links[l];
  }
  A1[idx] = (__bf16)v;
}

// ---- prep: D -> bf16 D1 [512][20096] (row copy) AND Dt [20096][512] (transpose) ----
__global__ __launch_bounds__(256) void prep_d(const float* __restrict__ D,
                                              __bf16* __restrict__ D1,
                                              __bf16* __restrict__ Dt) {
  __shared__ float t[32][33];
  int pb = blockIdx.x * 32;   // path block
  int lb = blockIdx.y * 32;   // link block
  for (int i = threadIdx.y; i < 32; i += 8) {
    int l = lb + i, p = pb + threadIdx.x;
    float v = (l < N_L && p < N_P) ? D[(size_t)l * N_P + p] : 0.f;
    t[i][threadIdx.x] = v;
    D1[(size_t)l * N_PP + p] = (__bf16)v;
  }
  __syncthreads();
  for (int i = threadIdx.y; i < 32; i += 8) {
    int p = pb + i, l = lb + threadIdx.x;
    Dt[(size_t)p * N_LP + l] = (__bf16)t[threadIdx.x][i];
  }
}

// ---- segment bounds: bounds[g] = first path index with seg >= g ----
__global__ __launch_bounds__(256) void seg_bounds(const int* __restrict__ seg,
                                                  int* __restrict__ bounds) {
  int g = blockIdx.x * 256 + threadIdx.x;
  if (g > N_G) return;
  int lo = 0, hi = N_P;
  while (lo < hi) { int mid = (lo + hi) >> 1; if (seg[mid] < g) lo = mid + 1; else hi = mid; }
  bounds[g] = lo;
}

// ---- GEMM (A and Bt row-major over K): C[m][n] = sum_k A[m][k]*Bt[n][k] ----
// 128x128 tile, 4 waves (2x2), BK=32 (m97 structure; BK=64 refuted R7/m132).
// ZSWZ=1: 1-D grid, z = bid&15 so XCD (= bid%8) pins z%8 -> each XCD's 2 K-chunks
// keep their D1 slices (~2.6 MB) L2-resident.
template <int ZSWZ>
__global__ __launch_bounds__(256) void gemm_bt(const __bf16* __restrict__ A,
                                               const __bf16* __restrict__ Bt,
                                               float* __restrict__ C,
                                               int lda, int ldb, int ldc,
                                               int K, int kchunk, size_t zstride) {
  int bx, by, bz;
  if (ZSWZ) { int bid = blockIdx.x; bz = bid & 15; bx = (bid >> 4) & 3; by = bid >> 6; }
  else      { bx = blockIdx.x; by = blockIdx.y; bz = blockIdx.z; }
  __shared__ __bf16 lsA[128 * 32];
  __shared__ __bf16 lsB[128 * 32];
  const int tid = threadIdx.x;
  const int lane = tid & 63;
  const int wv = tid >> 6;
  const int wr = wv >> 1, wc = wv & 1;
  const int m0 = by * 128;
  const int n0 = bx * 128;
  const int kb = bz * kchunk;
  const int klen = min(kchunk, K - kb);

  const int srow = wv * 16 + (lane >> 2);
  const int scol = (lane & 3) * 8;
  const __bf16* gA = A + (size_t)(m0 + srow) * lda + kb + scol;
  const __bf16* gB = Bt + (size_t)(n0 + srow) * ldb + kb + scol;
  __bf16* lA0 = &lsA[(wv * 16) * 32];
  __bf16* lA1 = &lsA[(64 + wv * 16) * 32];
  __bf16* lB0 = &lsB[(wv * 16) * 32];
  __bf16* lB1 = &lsB[(64 + wv * 16) * 32];

  f32x4 acc[4][4] = {};
  const int fra = (wr * 64 + (lane & 15)) * 32 + 8 * (lane >> 4);
  const int frb = (wc * 64 + (lane & 15)) * 32 + 8 * (lane >> 4);

  for (int kk = 0; kk < klen; kk += 32) {
    gload16(gA + kk, lA0);
    gload16(gA + (size_t)64 * lda + kk, lA1);
    gload16(gB + kk, lB0);
    gload16(gB + (size_t)64 * ldb + kk, lB1);
    __syncthreads();
    bf16x8 av[4], bv[4];
#pragma unroll
    for (int r = 0; r < 4; ++r) av[r] = *(const bf16x8*)&lsA[fra + r * 16 * 32];
#pragma unroll
    for (int c = 0; c < 4; ++c) bv[c] = *(const bf16x8*)&lsB[frb + c * 16 * 32];
#pragma unroll
    for (int r = 0; r < 4; ++r)
#pragma unroll
      for (int c = 0; c < 4; ++c)
        acc[r][c] = __builtin_amdgcn_mfma_f32_16x16x32_bf16(av[r], bv[c], acc[r][c], 0, 0, 0);
    __syncthreads();
  }

  float* Cz = C + (size_t)bz * zstride;
  const int erow = m0 + wr * 64 + (lane >> 4) * 4;
  const int ecol = n0 + wc * 64 + (lane & 15);
#pragma unroll
  for (int r = 0; r < 4; ++r)
#pragma unroll
    for (int c = 0; c < 4; ++c) {
      float* p = Cz + (size_t)(erow + r * 16) * ldc + (ecol + c * 16);
#pragma unroll
      for (int j = 0; j < 4; ++j) p[(size_t)j * ldc] = acc[r][c][j];
    }
}

// ---- grouped softmax: 1-WAVE blocks (64 threads), data-parallel over paths,
//      group reduce via LDS atomics. Single-wave => __syncthreads degenerates to
//      waitcnt (no cross-wave phase serialization) and 32 independent blocks/CU
//      co-reside to hide the L3-load latency chains (R10: 2 lock-stepped
//      blocks/SIMD, VALUBusy 42%, latency-bound at 96us). ----
__global__ __launch_bounds__(64) void seg_softmax(const float* __restrict__ vp,
                                                  const int* __restrict__ bounds,
                                                  const int* __restrict__ seg,
                                                  const float* __restrict__ q_sqrt,
                                                  __bf16* __restrict__ f) {
  __shared__ unsigned gmaxu[GQW];
  __shared__ float    den[GQW];    // denom, then overwritten with scale q^2/denom
  const int tid = threadIdx.x;
  const int b = blockIdx.x;
  const int g0 = blockIdx.y * GQW;
  const int g1 = g0 + GQW;

  const unsigned NEGINF = f2mono(-3.4e38f);
  for (int i = tid; i < GQW; i += 64) { gmaxu[i] = NEGINF; den[i] = 0.f; }

  const int s0 = bounds[g0];
  const int e0 = (blockIdx.y == NQW - 1) ? N_P : bounds[g1];
  const int s0a = s0 & ~3;
  const int e0a = (e0 + 3) & ~3;
  const float* row = vp + (size_t)b * N_PP;

  f32x4 vv[NCH] = {};
  i32x4 sg[NCH] = {};
  __syncthreads();   // init visible (single wave: waitcnt only)

  // pass 1: coalesced load into registers + run-combine atomic max
#define AMAX(g, m) { if ((g) >= g0 && (g) < g1) atomicMax(&gmaxu[(g) - g0], f2mono(m)); }
#pragma unroll
  for (int c = 0; c < NCH; ++c) {
    int p = s0a + (c * 64 + tid) * 4;
    if (p >= e0a) continue;
    f32x4 v = *(const f32x4*)&row[p];
    vv[c] = v;
    sg[c] = *(const i32x4*)&seg[p];
    int ga = sg[c][0]; float mv = v[0];
    if (sg[c][1] == ga) mv = fmaxf(mv, v[1]); else { AMAX(ga, mv); ga = sg[c][1]; mv = v[1]; }
    if (sg[c][2] == ga) mv = fmaxf(mv, v[2]); else { AMAX(ga, mv); ga = sg[c][2]; mv = v[2]; }
    if (sg[c][3] == ga) mv = fmaxf(mv, v[3]); else { AMAX(ga, mv); ga = sg[c][3]; mv = v[3]; }
    AMAX(ga, mv);
  }
#undef AMAX
  __syncthreads();

  // pass 2: exp (run-combined gmax lookup) + run-combine atomic add
#define AADD(g, s) { if ((g) >= g0 && (g) < g1) atomicAdd(&den[(g) - g0], s); }
#pragma unroll
  for (int c = 0; c < NCH; ++c) {
    int p = s0a + (c * 64 + tid) * 4;
    if (p >= e0a) continue;
    int grun = sg[c][0];
    bool gv = (grun >= g0 && grun < g1);
    float gm = gv ? mono2f(gmaxu[grun - g0]) : 0.f;
    float s = 0.f;
#pragma unroll
    for (int j = 0; j < 4; ++j) {
      int g = sg[c][j];
      if (g != grun) {
        AADD(grun, s);
        grun = g; s = 0.f;
        gv = (g >= g0 && g < g1);
        gm = gv ? mono2f(gmaxu[g - g0]) : 0.f;
      }
      float e = gv ? __expf(vv[c][j] - gm) : 0.f;
      vv[c][j] = e;
      s += e;
    }
    AADD(grun, s);
  }
#undef AADD
  __syncthreads();

  // den -> scale = q^2 / den
  for (int g = tid; g < GQW; g += 64) {
    float d = den[g];
    if (d > 0.f) {
      float qs = q_sqrt[g0 + g];
      den[g] = qs * qs / d;
    }
  }
  __syncthreads();

  // pass 3: scale (run-combined lookup) + store
  __bf16* frow = f + (size_t)b * N_PP;
#pragma unroll
  for (int c = 0; c < NCH; ++c) {
    int p = s0a + (c * 64 + tid) * 4;
    if (p >= e0a) continue;
    int grun = sg[c][0];
    bool gv = (grun >= g0 && grun < g1);
    float sc = gv ? den[grun - g0] : 0.f;
    bool allv = (sg[c][0] >= g0) && (sg[c][3] < g1);
    bf16x4 o;
    bool ok[4];
#pragma unroll
    for (int j = 0; j < 4; ++j) {
      int g = sg[c][j];
      if (g != grun) {
        grun = g;
        gv = (g >= g0 && g < g1);
        sc = gv ? den[g - g0] : 0.f;
      }
      ok[j] = gv;
      o[j] = (__bf16)(vv[c][j] * sc);
    }
    if (allv) {
      *(bf16x4*)&frow[p] = o;
    } else {
#pragma unroll
      for (int j = 0; j < 4; ++j)
        if (ok[j]) frow[p + j] = o[j];
    }
  }
  // zero padded tail so GEMM2's K-padding contributes nothing
  if (blockIdx.y == NQW - 1)
    for (int p = N_P + tid; p < N_PP; p += 64) frow[p] = (__bf16)0.f;
}

// ---- reduce split-K partials -> out (only l < 500) ----
__global__ __launch_bounds__(256) void reduce_out(const float* __restrict__ part,
                                                  float* __restrict__ out) {
  int idx = blockIdx.x * 256 + threadIdx.x;   // over 1536*500
  if (idx >= M_B * N_L) return;
  int b = idx / N_L, l = idx - b * N_L;
  float s = 0.f;
#pragma unroll
  for (int z = 0; z < SPLITK; ++z)
    s += part[(size_t)z * M_B * N_LP + (size_t)b * N_LP + l];
  out[idx] = s;
}

extern "C" void kernel_launch(void* const* d_in, const int* in_sizes, int n_in,
                              void* d_out, int out_size, void* d_ws, size_t ws_size,
                              hipStream_t stream) {
  const float* X           = (const float*)d_in[0];
  const float* theta       = (const float*)d_in[1];
  const float* theta_links = (const float*)d_in[2];
  const float* q_sqrt      = (const float*)d_in[3];
  const float* D           = (const float*)d_in[4];
  const int*   seg         = (const int*)d_in[5];
  float* out = (float*)d_out;

  char* ws = (char*)d_ws;
  __bf16* A1   = (__bf16*)(ws + OFF_A1);
  __bf16* D1   = (__bf16*)(ws + OFF_D1);
  __bf16* Dt   = (__bf16*)(ws + OFF_DT);
  float*  vp   = (float*)(ws + OFF_VP);
  float*  part = (float*)(ws + OFF_PART);
  __bf16* fbuf = (__bf16*)(ws + OFF_F);
  int*    bnd  = (int*)(ws + OFF_BND);

  prep_a1<<<(M_B * N_LP) / 256, 256, 0, stream>>>(X, theta, theta_links, A1);
  prep_d<<<dim3(N_PP / 32, N_LP / 32), dim3(32, 8), 0, stream>>>(D, D1, Dt);
  seg_bounds<<<16, 256, 0, stream>>>(seg, bnd);

  // GEMM1: vp[b][p] = sum_l A1[b][l] * Dt[p][l]
  gemm_bt<0><<<dim3(N_PP / 128, M_B / 128, 1), 256, 0, stream>>>(
      A1, Dt, vp, N_LP, N_LP, N_PP, N_LP, N_LP, (size_t)0);

  // softmax: 1-wave blocks, grid (1536 rows, 32 group-slices)
  seg_softmax<<<dim3(M_B, NQW), 64, 0, stream>>>(vp, bnd, seg, q_sqrt, fbuf);

  // GEMM2 (split-K, z-swizzled 1-D grid): part[z][b][l] = sum_{k in z} f[b][k]*D1[l][k]
  gemm_bt<1><<<dim3((N_LP / 128) * (M_B / 128) * SPLITK, 1, 1), 256, 0, stream>>>(
      fbuf, D1, part, N_PP, N_PP, N_LP, N_PP, KCHUNK2, (size_t)(M_B * N_LP));

  reduce_out<<<(M_B * N_L + 255) / 256, 256, 0, stream>>>(part, out);
}